// Round 1
// baseline (230.306 us; speedup 1.0000x reference)
//
#include <hip/hip_runtime.h>
#include <hip/hip_bf16.h>

// ContrastiveLoss: B=4096 rows, D=128 feature dim, C=100 classes.
// loss = -(1/B^2) * sum_c count_c * G_c / (count_c + 1e-12)
//   G_c  = sum_{k: label_k=c} S_k
//   S_k  = sum_j logits[k,j] - B*m_k - B*log(Z_k + 1e-12)
//   logits[k,j] = w_k . a_j,  w_k = (a_k + (a_k @ Cov[l_k]) / (2 T^2)) / T

#define DIM 128
#define TEMP 0.07f

__global__ void count_kernel(const int* __restrict__ labels,
                             int* __restrict__ counts, int B) {
    int i = blockIdx.x * 256 + threadIdx.x;
    if (i < B) atomicAdd(&counts[labels[i]], 1);
}

// One block per row i: w_i[e] = (a_i[e] + (sum_d a_i[d]*Cov[c][d][e]) * inv2t2) * invt
__global__ __launch_bounds__(128) void w_kernel(
    const float* __restrict__ A, const int* __restrict__ labels,
    const float* __restrict__ Cov, float* __restrict__ W) {
    const float inv2t2 = 1.0f / (2.0f * TEMP * TEMP);
    const float invt = 1.0f / TEMP;
    int i = blockIdx.x;
    int e = threadIdx.x;
    __shared__ float a[DIM];
    a[e] = A[(size_t)i * DIM + e];
    __syncthreads();
    int c = labels[i];
    const float* Cp = Cov + (size_t)c * (DIM * DIM) + e;
    float acc = 0.0f;
#pragma unroll 8
    for (int d = 0; d < DIM; ++d) {
        acc = fmaf(a[d], Cp[(size_t)d * DIM], acc);
    }
    W[(size_t)i * DIM + e] = (a[e] + acc * inv2t2) * invt;
}

// Lane = one row k (w_k in 128 VGPRs). Wave iterates a 64-column j-chunk,
// maintaining per-lane online softmax state (m, Z, sumLogits).
// grid = (B/64 j-chunks) x (B/64 k-blocks), block = 64 threads (1 wave).
__global__ __launch_bounds__(64) void main_kernel(
    const float* __restrict__ A, const float* __restrict__ W,
    float* __restrict__ mP, float* __restrict__ zP, float* __restrict__ sP,
    int B) {
    int nJB = B >> 6;
    int jb = blockIdx.x % nJB;
    int kb = blockIdx.x / nJB;
    int lane = threadIdx.x;
    int k = kb * 64 + lane;

    // Load w_k into registers (per-lane distinct -> vector loads).
    float4 w[DIM / 4];
    const float4* wp = (const float4*)(W + (size_t)k * DIM);
#pragma unroll
    for (int d = 0; d < DIM / 4; ++d) w[d] = wp[d];

    float m = -3.4e38f, Z = 0.0f, sL = 0.0f;
    const float4* ap = (const float4*)(A + (size_t)jb * 64 * DIM);

    for (int jj = 0; jj < 64; ++jj) {
        const float4* aj = ap + jj * (DIM / 4);
        float dot = 0.0f;
#pragma unroll
        for (int d = 0; d < DIM / 4; ++d) {
            float4 av = aj[d];  // wave-uniform address -> broadcast
            dot = fmaf(w[d].x, av.x, dot);
            dot = fmaf(w[d].y, av.y, dot);
            dot = fmaf(w[d].z, av.z, dot);
            dot = fmaf(w[d].w, av.w, dot);
        }
        sL += dot;
        float mn = fmaxf(m, dot);
        Z = Z * __expf(m - mn) + __expf(dot - mn);
        m = mn;
    }
    size_t idx = (size_t)k * nJB + jb;
    mP[idx] = m;
    zP[idx] = Z;
    sP[idx] = sL;
}

// One wave per row k: merge the nJB partial (m,Z,s) triples, compute S_k,
// accumulate into per-class G (double atomics).
__global__ __launch_bounds__(64) void combine_kernel(
    const float* __restrict__ mP, const float* __restrict__ zP,
    const float* __restrict__ sP, const int* __restrict__ labels,
    double* __restrict__ G, int B) {
    int k = blockIdx.x;
    int l = threadIdx.x;
    int nJB = B >> 6;
    float m = -3.4e38f, Z = 0.0f, s = 0.0f;
    if (l < nJB) {
        size_t idx = (size_t)k * nJB + l;
        m = mP[idx];
        Z = zP[idx];
        s = sP[idx];
    }
    float M = m;
#pragma unroll
    for (int o = 32; o > 0; o >>= 1) M = fmaxf(M, __shfl_xor(M, o));
    float zt = Z * __expf(m - M);
    float st = s;
#pragma unroll
    for (int o = 32; o > 0; o >>= 1) {
        zt += __shfl_xor(zt, o);
        st += __shfl_xor(st, o);
    }
    if (l == 0) {
        double Sk = (double)st - (double)B * (double)M
                    - (double)B * log((double)zt + 1e-12);
        atomicAdd(&G[labels[k]], Sk);
    }
}

__global__ __launch_bounds__(128) void final_kernel(
    const double* __restrict__ G, const int* __restrict__ counts,
    float* __restrict__ out, int C, double invB2) {
    __shared__ double sh[128];
    int t = threadIdx.x;
    double v = 0.0;
    if (t < C) {
        double cnt = (double)counts[t];
        v = G[t] * (cnt / (cnt + 1e-12));
    }
    sh[t] = v;
    __syncthreads();
    for (int o = 64; o > 0; o >>= 1) {
        if (t < o) sh[t] += sh[t + o];
        __syncthreads();
    }
    if (t == 0) out[0] = (float)(-sh[0] * invB2);
}

extern "C" void kernel_launch(void* const* d_in, const int* in_sizes, int n_in,
                              void* d_out, int out_size, void* d_ws, size_t ws_size,
                              hipStream_t stream) {
    const float* A = (const float*)d_in[0];
    const int* labels = (const int*)d_in[1];
    const float* Cov = (const float*)d_in[2];
    float* out = (float*)d_out;

    int B = in_sizes[0] / DIM;            // 4096
    int C = in_sizes[2] / (DIM * DIM);    // 100
    int nJB = B >> 6;                     // 64

    char* ws = (char*)d_ws;
    float* W = (float*)ws;                                    // B*128 f32 (2 MB)
    float* mP = (float*)(ws + (size_t)B * DIM * 4);           // B*nJB f32 (1 MB)
    float* zP = mP + (size_t)B * nJB;
    float* sP = zP + (size_t)B * nJB;
    double* G = (double*)(sP + (size_t)B * nJB);              // C doubles
    int* counts = (int*)(G + C);                              // C ints

    // zero G + counts (contiguous)
    hipMemsetAsync(G, 0, (size_t)C * (sizeof(double) + sizeof(int)), stream);

    count_kernel<<<(B + 255) / 256, 256, 0, stream>>>(labels, counts, B);
    w_kernel<<<B, 128, 0, stream>>>(A, labels, Cov, W);
    main_kernel<<<nJB * (B / 64), 64, 0, stream>>>(A, W, mP, zP, sP, B);
    combine_kernel<<<B, 64, 0, stream>>>(mP, zP, sP, labels, G, B);
    final_kernel<<<1, 128, 0, stream>>>(G, counts, out, C,
                                        1.0 / ((double)B * (double)B));
}